// Round 6
// baseline (1181.553 us; speedup 1.0000x reference)
//
#include <hip/hip_runtime.h>
#include <hip/hip_bf16.h>

typedef unsigned short ushort_t;
typedef __bf16 bf16x8 __attribute__((ext_vector_type(8)));
typedef unsigned short ushort8 __attribute__((ext_vector_type(8)));
typedef unsigned short ushort4v __attribute__((ext_vector_type(4)));
typedef float f32x4 __attribute__((ext_vector_type(4)));

#define HH 128          // hidden dim
#define EPS 1e-5f
#define STAT_SLICES 32
#define MTILE 32        // mm1 tile rows
#define FB 1024         // fused kernel grid: 4 blocks/CU x 256 CU (co-resident by construction)

__device__ __forceinline__ float bf2f(ushort_t u) {
    unsigned v = ((unsigned)u) << 16;
    return __builtin_bit_cast(float, v);
}
__device__ __forceinline__ ushort_t f2bf(float f) {
    unsigned u = __builtin_bit_cast(unsigned, f);
    unsigned r = (u + 0x7fffu + ((u >> 16) & 1u)) >> 16;
    return (ushort_t)r;
}
__device__ __forceinline__ float cvt(const void* p, int i, int flag) {
    return flag ? bf2f(((const ushort_t*)p)[i]) : ((const float*)p)[i];
}
// accumulate 8 bf16 channels (one uint4) scaled by c into a[8]
__device__ __forceinline__ void acc8(const uint4 w, float c, float a[8]) {
    unsigned x0 = w.x, x1 = w.y, x2 = w.z, x3 = w.w;
    a[0] = fmaf(__builtin_bit_cast(float, x0 << 16), c, a[0]);
    a[1] = fmaf(__builtin_bit_cast(float, x0 & 0xffff0000u), c, a[1]);
    a[2] = fmaf(__builtin_bit_cast(float, x1 << 16), c, a[2]);
    a[3] = fmaf(__builtin_bit_cast(float, x1 & 0xffff0000u), c, a[3]);
    a[4] = fmaf(__builtin_bit_cast(float, x2 << 16), c, a[4]);
    a[5] = fmaf(__builtin_bit_cast(float, x2 & 0xffff0000u), c, a[5]);
    a[6] = fmaf(__builtin_bit_cast(float, x3 << 16), c, a[6]);
    a[7] = fmaf(__builtin_bit_cast(float, x3 & 0xffff0000u), c, a[7]);
}

// device-wide barrier: all FB blocks co-resident (enforced via __launch_bounds__+grid).
// cnt: monotone arrival counter; rel: release epoch. Both zeroed per launch.
__device__ __forceinline__ void gridSync(int* cnt, int* rel, int phase, int nb) {
    __syncthreads();
    if (threadIdx.x == 0) {
        __threadfence();                       // release: my phase writes visible
        int prev = atomicAdd(cnt, 1);
        if (prev == nb * phase - 1) {
            atomicExch(rel, phase);            // last arriver opens gate
        } else {
            while (atomicAdd(rel, 0) < phase) __builtin_amdgcn_s_sleep(8);
        }
        __threadfence();                       // acquire: invalidate stale caches
    }
    __syncthreads();
}

// ================= fused pre-kernel: hist | weight-transpose | setup =================
// Wt stored UNPADDED row-major: Wt1[128][256], Wt2/3[128][128]
__global__ void preK(const int* __restrict__ dst, int* __restrict__ counts, int E,
                     const void* W1, ushort_t* Wt1, const void* W2, ushort_t* Wt2,
                     const void* W3, ushort_t* Wt3,
                     const void* g1, const void* b1, const void* b2, const void* b3,
                     const void* g2, const void* g3, const void* be1, const void* be2,
                     const void* be3, const void* Wfp, const void* bfp,
                     float* __restrict__ cvec, int histB) {
    const int bid = blockIdx.x;
    const int tid = threadIdx.x;
    const int flag = (((const ushort_t*)g1)[0] == 0x3F80) ? 1 : 0;
    if (bid < histB) {
        int e = bid * 256 + tid;
        if (e < E) atomicAdd(&counts[dst[e]], 1);
    } else if (bid < histB + 256) {
        int idx = (bid - histB) * 256 + tid;   // 0..65535
        const void* W; ushort_t* Wt; int K;
        if (idx < 32768)      { W = W1; Wt = Wt1; K = 256; }
        else if (idx < 49152) { W = W2; Wt = Wt2; K = 128; idx -= 32768; }
        else                  { W = W3; Wt = Wt3; K = 128; idx -= 49152; }
        int k = idx >> 7, nn = idx & 127;
        Wt[nn * K + k] = flag ? ((const ushort_t*)W)[idx] : f2bf(((const float*)W)[idx]);
    } else {
        int t = tid;
        if (t < 128) {
            cvec[t]        = cvt(b1, t, flag);
            cvec[128 + t]  = cvt(b2, t, flag);
            cvec[256 + t]  = cvt(b3, t, flag);
            cvec[384 + t]  = cvt(g1, t, flag);
            cvec[512 + t]  = cvt(g2, t, flag);
            cvec[640 + t]  = cvt(g3, t, flag);
            cvec[768 + t]  = cvt(be1, t, flag);
            cvec[896 + t]  = cvt(be2, t, flag);
            cvec[1024 + t] = cvt(be3, t, flag);
            cvec[1152 + t] = cvt(Wfp, t, flag);
            if (t == 0) cvec[1280] = cvt(bfp, 0, flag);
        }
    }
}

// ================= fused: scanA (block sums) | disK =================
__global__ void scanAdisK(const int* __restrict__ cnt, int* __restrict__ partial,
                          float* __restrict__ dis, int n, int nbScan) {
    __shared__ int lds[256];
    const int tid = threadIdx.x;
    if ((int)blockIdx.x < nbScan) {
        int base = blockIdx.x * 2048 + tid * 8;
        int s = 0;
#pragma unroll
        for (int j = 0; j < 8; ++j) { int idx = base + j; if (idx < n) s += cnt[idx]; }
        lds[tid] = s; __syncthreads();
        for (int off = 128; off; off >>= 1) { if (tid < off) lds[tid] += lds[tid + off]; __syncthreads(); }
        if (tid == 0) partial[blockIdx.x] = lds[0];
    } else {
        int i = (blockIdx.x - nbScan) * 256 + tid;
        if (i < n) dis[i] = rsqrtf((float)cnt[i] + 1.0f);
    }
}

// scanC with local recompute of the partial prefix
__device__ __forceinline__ void scanC2Dev(int* lds, const int* __restrict__ cnt,
                                          const int* __restrict__ partial,
                                          int* __restrict__ rowptr, int n, int bid, int nb) {
    const int tid = threadIdx.x;
    int pre = 0, tot = 0;
    for (int i = 0; i < nb; ++i) { int v = partial[i]; if (i < bid) pre += v; tot += v; }
    int base = bid * 2048 + tid * 8;
    int v[8]; int s = 0;
#pragma unroll
    for (int j = 0; j < 8; ++j) { int idx = base + j; v[j] = (idx < n) ? cnt[idx] : 0; s += v[j]; }
    lds[tid] = s; __syncthreads();
    for (int off = 1; off < 256; off <<= 1) {
        int x = (tid >= off) ? lds[tid - off] : 0;
        __syncthreads();
        lds[tid] += x;
        __syncthreads();
    }
    int excl = lds[tid] - s;
    int off0 = pre + excl;
#pragma unroll
    for (int j = 0; j < 8; ++j) {
        int idx = base + j;
        if (idx < n) { rowptr[idx] = off0; off0 += v[j]; }
    }
    if (bid == 0 && tid == 0) rowptr[n] = tot;
}

// ================= mm layer1 (K=256): W in REGISTERS, cooperative bf16 A staging ======
__global__ __launch_bounds__(256) void mm1scanCK(const void* __restrict__ x,
                                                 const ushort_t* __restrict__ Wt1,
                                                 ushort_t* __restrict__ tbuf, int n,
                                                 const ushort_t* __restrict__ flagRef,
                                                 const int* __restrict__ cnt,
                                                 const int* __restrict__ partial,
                                                 int* __restrict__ rowptr, int nbScan) {
    __shared__ char smem[33792];           // 2 x 16KB A bufs | scanC scratch (1KB)
    const int tid = threadIdx.x;
    if ((int)blockIdx.x < nbScan) {
        scanC2Dev((int*)smem, cnt, partial, rowptr, n, blockIdx.x, nbScan);
        return;
    }
    const int arm = blockIdx.x - nbScan;
    const int NB  = gridDim.x - nbScan;
    const int nTiles = (n + MTILE - 1) / MTILE;
    if (arm >= nTiles) return;

    const int lane = tid & 63, wave = tid >> 6;
    const int m = lane & 15, q = lane >> 4;
    const int flag = (flagRef[0] == 0x3F80) ? 1 : 0;

    // ---- W fragments in registers: wave w covers out-ch groups t = 2w, 2w+1
    ushort8 wfrag[8][2];
#pragma unroll
    for (int s = 0; s < 8; ++s)
#pragma unroll
        for (int tt = 0; tt < 2; ++tt)
            wfrag[s][tt] = *(const ushort8*)&Wt1[(size_t)((wave * 2 + tt) * 16 + m) * 256 + s * 32 + q * 8];

    // staging thread mapping: row sr (0..31), 32 cols starting at sa*32
    const int sr = tid >> 3, sa = tid & 7;
    char* buf0 = smem;
    char* buf1 = smem + 16384;

    float4  f[8];
    ushort8 v[4];

    auto stageLoad = [&](int T) {
        int row = T * MTILE + sr; if (row >= n) row = n - 1;
        if (flag) {
            const ushort_t* xp = (const ushort_t*)x + (size_t)row * 256 + sa * 32;
#pragma unroll
            for (int j = 0; j < 4; ++j) v[j] = *(const ushort8*)(xp + j * 8);
        } else {
            const float* xp = (const float*)x + (size_t)row * 256 + sa * 32;
#pragma unroll
            for (int j = 0; j < 8; ++j) f[j] = *(const float4*)(xp + j * 4);
        }
    };
    auto convWrite = [&](char* buf) {
        if (!flag) {
#pragma unroll
            for (int j = 0; j < 4; ++j) {
                float4 a = f[2 * j], b = f[2 * j + 1];
                ushort8 t8;
                t8[0] = f2bf(a.x); t8[1] = f2bf(a.y); t8[2] = f2bf(a.z); t8[3] = f2bf(a.w);
                t8[4] = f2bf(b.x); t8[5] = f2bf(b.y); t8[6] = f2bf(b.z); t8[7] = f2bf(b.w);
                v[j] = t8;
            }
        }
#pragma unroll
        for (int j = 0; j < 4; ++j) {
            int u = (sa * 4 + j) ^ (sr & 7);
            *(ushort8*)(buf + sr * 512 + u * 16) = v[j];
        }
    };
    auto computeStore = [&](int T, const char* buf) {
        f32x4 acc[2][2];
#pragma unroll
        for (int bb = 0; bb < 2; ++bb)
#pragma unroll
            for (int tt = 0; tt < 2; ++tt) acc[bb][tt] = (f32x4){0.f, 0.f, 0.f, 0.f};
#pragma unroll
        for (int bb = 0; bb < 2; ++bb) {
            const char* base = buf + (bb * 16 + m) * 512;
#pragma unroll
            for (int s = 0; s < 8; ++s) {
                ushort8 xf = *(const ushort8*)(base + (((s * 4 + q) ^ (m & 7)) * 16));
                bf16x8 xb = __builtin_bit_cast(bf16x8, xf);
#pragma unroll
                for (int tt = 0; tt < 2; ++tt)
                    acc[bb][tt] = __builtin_amdgcn_mfma_f32_16x16x32_bf16(
                        __builtin_bit_cast(bf16x8, wfrag[s][tt]), xb, acc[bb][tt], 0, 0, 0);
            }
        }
#pragma unroll
        for (int bb = 0; bb < 2; ++bb) {
            int node = T * MTILE + bb * 16 + m;
            if (node < n) {
#pragma unroll
                for (int tt = 0; tt < 2; ++tt) {
                    ushort4v pk;
#pragma unroll
                    for (int r = 0; r < 4; ++r) pk[r] = f2bf(acc[bb][tt][r]);
                    *(ushort4v*)(tbuf + (size_t)node * HH + (wave * 2 + tt) * 16 + q * 4) = pk;
                }
            }
        }
    };

    // prologue
    stageLoad(arm); convWrite(buf0);
    __syncthreads();
    int T = arm, pp = 0;
    while (true) {
        int Tn = T + NB;
        bool more = (Tn < nTiles);
        if (more) stageLoad(Tn);               // issue next-tile loads early
        computeStore(T, pp ? buf1 : buf0);     // hide load latency under MFMAs
        if (!more) break;
        convWrite(pp ? buf0 : buf1);
        __syncthreads();
        T = Tn; pp ^= 1;
    }
}

// ================= fused post-mm1 chain: scatter|agg1|mm2|agg2|mm3|agg3|out ===========
// One kernel, 6 device-wide barriers. 1024 blocks x 256 thr, 4 blocks/CU co-resident
// (launch_bounds caps VGPR at 128; LDS 17.4KB). mm phases: W in regs (32 VGPR),
// reg-staged XOR-swizzled A tiles (2x8KB dbuf).
__global__ __launch_bounds__(256, 4) void fusedK(
        const int* __restrict__ src, const int* __restrict__ dst,
        const int* __restrict__ rowptr, int* __restrict__ fill,
        const float* __restrict__ dis, uint2* __restrict__ erec, int E,
        const ushort_t* __restrict__ Wt2, const ushort_t* __restrict__ Wt3,
        ushort_t* __restrict__ tbuf, ushort_t* __restrict__ gbuf,
        const float* __restrict__ cvec, float* __restrict__ stats,
        void* __restrict__ outv, int n, const ushort_t* __restrict__ flagRef,
        int* __restrict__ bcnt, int* __restrict__ brel) {
    __shared__ char smem[17408];           // mm: 2x8KB A dbuf + 1KB scw | agg: 4KB red
    const int NB  = gridDim.x;
    const int tid = threadIdx.x;
    const int lane = tid & 63, wave = tid >> 6;

    const float* c_b1  = cvec;        const float* c_b2  = cvec + 128;
    const float* c_b3  = cvec + 256;  const float* c_g1  = cvec + 384;
    const float* c_g2  = cvec + 512;  const float* c_g3  = cvec + 640;
    const float* c_be1 = cvec + 768;  const float* c_be2 = cvec + 896;
    const float* c_be3 = cvec + 1024; const float* c_Wf  = cvec + 1152;
    const float* c_bf  = cvec + 1280;
    float* ssum0 = stats;            float* ssq0 = stats + 4096;
    float* ssum1 = stats + 8192;     float* ssq1 = stats + 12288;
    float* ssum2 = stats + 16384;    float* ssq2 = stats + 20480;

    // ---------------- P0: CSR scatter ----------------
    for (int e = blockIdx.x * 256 + tid; e < E; e += NB * 256) {
        int d = dst[e], s = src[e];
        int old = atomicSub(&fill[d], 1);
        int pos = rowptr[d] + old - 1;
        float c = dis[s] * dis[d];
        uint2 r; r.x = (unsigned)s; r.y = __builtin_bit_cast(unsigned, c);
        erec[pos] = r;
    }

    // ---------------- agg phase (t -> g, bias, stats) ----------------
    auto aggPhase = [&](const ushort_t* __restrict__ t, ushort_t* __restrict__ g,
                        const float* __restrict__ bias,
                        float* __restrict__ ssum, float* __restrict__ ssq) {
        const int grp = lane >> 4, p = lane & 15, cb = p * 8;
        float bch[8];
#pragma unroll
        for (int j = 0; j < 8; ++j) bch[j] = bias[cb + j];
        float s[8], q[8];
#pragma unroll
        for (int j = 0; j < 8; ++j) { s[j] = 0.f; q[j] = 0.f; }

        for (int node = blockIdx.x * 16 + wave * 4 + grp; node < n; node += NB * 16) {
            float d = dis[node];
            float d2 = d * d;
            float a[8];
#pragma unroll
            for (int j = 0; j < 8; ++j) a[j] = 0.f;
            uint4 sv = *(const uint4*)(t + (size_t)node * HH + cb);
            acc8(sv, d2, a);

            const int beg = rowptr[node], end = rowptr[node + 1];
            int e = beg;
            for (; e + 8 <= end; e += 8) {
                uint2 rr[8];
#pragma unroll
                for (int kk = 0; kk < 8; ++kk) rr[kk] = erec[e + kk];
                uint4 w0[4];
#pragma unroll
                for (int kk = 0; kk < 4; ++kk)
                    w0[kk] = *(const uint4*)(t + (size_t)rr[kk].x * HH + cb);
                uint4 w1[4];
#pragma unroll
                for (int kk = 0; kk < 4; ++kk)
                    w1[kk] = *(const uint4*)(t + (size_t)rr[4 + kk].x * HH + cb);
#pragma unroll
                for (int kk = 0; kk < 4; ++kk)
                    acc8(w0[kk], __builtin_bit_cast(float, rr[kk].y), a);
#pragma unroll
                for (int kk = 0; kk < 4; ++kk)
                    acc8(w1[kk], __builtin_bit_cast(float, rr[4 + kk].y), a);
            }
            if (e < end) {
                uint2 rr[8];
#pragma unroll
                for (int kk = 0; kk < 8; ++kk) {
                    int idx = e + kk;
                    rr[kk] = (idx < end) ? erec[idx] : (uint2){0u, 0u};
                }
                uint4 w0[4];
#pragma unroll
                for (int kk = 0; kk < 4; ++kk)
                    w0[kk] = *(const uint4*)(t + (size_t)rr[kk].x * HH + cb);
                uint4 w1[4];
#pragma unroll
                for (int kk = 0; kk < 4; ++kk)
                    w1[kk] = *(const uint4*)(t + (size_t)rr[4 + kk].x * HH + cb);
#pragma unroll
                for (int kk = 0; kk < 4; ++kk)
                    acc8(w0[kk], __builtin_bit_cast(float, rr[kk].y), a);
#pragma unroll
                for (int kk = 0; kk < 4; ++kk)
                    acc8(w1[kk], __builtin_bit_cast(float, rr[4 + kk].y), a);
            }

            ushort8 pk;
#pragma unroll
            for (int j = 0; j < 8; ++j) {
                a[j] += bch[j];
                pk[j] = f2bf(a[j]);
                s[j] += a[j]; q[j] += a[j] * a[j];
            }
            *(ushort8*)(g + (size_t)node * HH + cb) = pk;
        }

#pragma unroll
        for (int j = 0; j < 8; ++j) {
            s[j] += __shfl_xor(s[j], 16); s[j] += __shfl_xor(s[j], 32);
            q[j] += __shfl_xor(q[j], 16); q[j] += __shfl_xor(q[j], 32);
        }
        float (*red)[16][16] = (float (*)[16][16])smem;
        __syncthreads();                       // smem free from prior phase
        if (grp == 0) {
#pragma unroll
            for (int j = 0; j < 8; ++j) { red[wave][p][j] = s[j]; red[wave][p][8 + j] = q[j]; }
        }
        __syncthreads();
        {
            int ch = tid & 127, kind = tid >> 7;
            float S = 0.f;
#pragma unroll
            for (int w = 0; w < 4; ++w) S += red[w][ch >> 3][kind * 8 + (ch & 7)];
            int slice = (blockIdx.x & (STAT_SLICES - 1)) * HH;
            atomicAdd((kind ? ssq : ssum) + slice + ch, S);
        }
    };

    // ---------------- mm+BN phase (A -> out, K=128, W in regs) ----------------
    auto mmPhase = [&](const ushort_t* __restrict__ A, const ushort_t* __restrict__ Wt,
                       ushort_t* __restrict__ out,
                       const float* __restrict__ ssum, const float* __restrict__ ssq,
                       const float* __restrict__ gam, const float* __restrict__ bet) {
        float* scw = (float*)(smem + 16384);
        if (tid < 128) {
            float S = 0.f, Q = 0.f;
#pragma unroll
            for (int sl = 0; sl < STAT_SLICES; ++sl) { S += ssum[sl * HH + tid]; Q += ssq[sl * HH + tid]; }
            float invn = 1.0f / (float)n;
            float mu = S * invn;
            float var = fmaxf(Q * invn - mu * mu, 0.f);
            float sc = gam[tid] * rsqrtf(var + EPS);
            scw[tid] = sc;
            scw[128 + tid] = bet[tid] - mu * sc;
        }
        const int m = lane & 15, q4 = lane >> 4;
        ushort8 wfrag[4][2];
#pragma unroll
        for (int s = 0; s < 4; ++s)
#pragma unroll
            for (int tt = 0; tt < 2; ++tt)
                wfrag[s][tt] = *(const ushort8*)&Wt[(size_t)((wave * 2 + tt) * 16 + m) * 128 + s * 32 + q4 * 8];

        const int sr = tid >> 3, sa = tid & 7;   // stage: row sr (0..31), 32B block sa
        char* b0 = smem;
        char* b1 = smem + 8192;
        ushort8 sv[2];

        auto sLoad = [&](int T) {
            int row = T * 32 + sr; if (row >= n) row = n - 1;
            const ushort_t* ap = A + (size_t)row * HH + sa * 16;
            sv[0] = *(const ushort8*)ap;
            sv[1] = *(const ushort8*)(ap + 8);
        };
        auto sWrite = [&](char* buf) {
#pragma unroll
            for (int j = 0; j < 2; ++j) {
                int u = (sa * 2 + j) ^ (sr & 7);
                *(ushort8*)(buf + sr * 256 + u * 16) = sv[j];
            }
        };
        auto comp = [&](int T, const char* buf) {
            f32x4 acc[2][2];
#pragma unroll
            for (int bb = 0; bb < 2; ++bb)
#pragma unroll
                for (int tt = 0; tt < 2; ++tt) acc[bb][tt] = (f32x4){0.f, 0.f, 0.f, 0.f};
#pragma unroll
            for (int bb = 0; bb < 2; ++bb) {
                const char* arow = buf + (bb * 16 + m) * 256;
#pragma unroll
                for (int s = 0; s < 4; ++s) {
                    ushort8 av = *(const ushort8*)(arow + (((s * 4 + q4) ^ (m & 7)) * 16));
                    int kb = s * 32 + q4 * 8;
#pragma unroll
                    for (int j = 0; j < 8; ++j)
                        av[j] = f2bf(fmaxf(bf2f(av[j]) * scw[kb + j] + scw[128 + kb + j], 0.f));
                    bf16x8 nf = __builtin_bit_cast(bf16x8, av);
#pragma unroll
                    for (int tt = 0; tt < 2; ++tt)
                        acc[bb][tt] = __builtin_amdgcn_mfma_f32_16x16x32_bf16(
                            __builtin_bit_cast(bf16x8, wfrag[s][tt]), nf, acc[bb][tt], 0, 0, 0);
                }
            }
#pragma unroll
            for (int bb = 0; bb < 2; ++bb) {
                int node = T * 32 + bb * 16 + m;
                if (node < n) {
#pragma unroll
                    for (int tt = 0; tt < 2; ++tt) {
                        ushort4v pk;
#pragma unroll
                        for (int r = 0; r < 4; ++r) pk[r] = f2bf(acc[bb][tt][r]);
                        *(ushort4v*)(out + (size_t)node * HH + (wave * 2 + tt) * 16 + q4 * 4) = pk;
                    }
                }
            }
        };

        const int nT = (n + 31) >> 5;
        int T = blockIdx.x, pp = 0;
        if (T < nT) sLoad(T);
        __syncthreads();                       // scw ready; smem free from prior phase
        if (T < nT) sWrite(b0);
        __syncthreads();
        while (T < nT) {
            int Tn = T + NB;
            if (Tn < nT) sLoad(Tn);
            comp(T, pp ? b1 : b0);
            if (Tn >= nT) break;
            sWrite(pp ? b0 : b1);
            __syncthreads();
            T = Tn; pp ^= 1;
        }
    };

    // ---------------- phase chain ----------------
    gridSync(bcnt, brel, 1, NB);
    aggPhase(tbuf, gbuf, c_b1, ssum0, ssq0);
    gridSync(bcnt, brel, 2, NB);
    mmPhase(gbuf, Wt2, tbuf, ssum0, ssq0, c_g1, c_be1);
    gridSync(bcnt, brel, 3, NB);
    aggPhase(tbuf, gbuf, c_b2, ssum1, ssq1);
    gridSync(bcnt, brel, 4, NB);
    mmPhase(gbuf, Wt3, tbuf, ssum1, ssq1, c_g2, c_be2);
    gridSync(bcnt, brel, 5, NB);
    aggPhase(tbuf, gbuf, c_b3, ssum2, ssq2);
    gridSync(bcnt, brel, 6, NB);

    // ---------------- P6: output head ----------------
    {
        float* scw = (float*)(smem + 16384);
        if (tid < 128) {
            float S = 0.f, Q = 0.f;
#pragma unroll
            for (int sl = 0; sl < STAT_SLICES; ++sl) { S += ssum2[sl * HH + tid]; Q += ssq2[sl * HH + tid]; }
            float invn = 1.0f / (float)n;
            float mu = S * invn;
            float var = fmaxf(Q * invn - mu * mu, 0.f);
            float sc = c_g3[tid] * rsqrtf(var + EPS);
            scw[tid] = sc;
            scw[128 + tid] = c_be3[tid] - mu * sc;
        }
        __syncthreads();

        const int grp = lane >> 4, p = lane & 15, cb = p * 8;
        float w8[8], sc8[8], sh8[8];
#pragma unroll
        for (int j = 0; j < 8; ++j) {
            w8[j] = c_Wf[cb + j]; sc8[j] = scw[cb + j]; sh8[j] = scw[128 + cb + j];
        }
        const float bb = c_bf[0];
        const int flag = (flagRef[0] == 0x3F80) ? 1 : 0;

        for (int node = blockIdx.x * 16 + wave * 4 + grp; node < n; node += NB * 16) {
            uint4 v = *(const uint4*)(gbuf + (size_t)node * HH + cb);
            unsigned u[4] = {v.x, v.y, v.z, v.w};
            float x = 0.f;
#pragma unroll
            for (int j = 0; j < 4; ++j) {
                float f0 = __builtin_bit_cast(float, u[j] << 16);
                float f1 = __builtin_bit_cast(float, u[j] & 0xffff0000u);
                x += fmaxf(f0 * sc8[2 * j] + sh8[2 * j], 0.f) * w8[2 * j];
                x += fmaxf(f1 * sc8[2 * j + 1] + sh8[2 * j + 1], 0.f) * w8[2 * j + 1];
            }
#pragma unroll
            for (int off = 8; off; off >>= 1) x += __shfl_xor(x, off);
            if (p == 0) {
                float r = x + bb;
                if (flag) ((ushort_t*)outv)[node] = f2bf(r);
                else      ((float*)outv)[node] = r;
            }
        }
    }
}

// ================= launch =================
extern "C" void kernel_launch(void* const* d_in, const int* in_sizes, int n_in,
                              void* d_out, int out_size, void* d_ws, size_t ws_size,
                              hipStream_t stream) {
    const int DIN = 256;
    const int N = in_sizes[0] / DIN;
    const int E = in_sizes[1];

    const void* x   = d_in[0];
    const int*  src = (const int*)d_in[1];
    const int*  dst = (const int*)d_in[2];
    const void* W1  = d_in[3];
    const void* b1  = d_in[4];
    const void* g1  = d_in[5];
    const void* be1 = d_in[6];
    const void* W2  = d_in[7];
    const void* b2  = d_in[8];
    const void* g2  = d_in[9];
    const void* be2 = d_in[10];
    const void* W3  = d_in[11];
    const void* b3  = d_in[12];
    const void* g3  = d_in[13];
    const void* be3 = d_in[14];
    const void* Wf  = d_in[15];
    const void* bfp = d_in[16];
    const ushort_t* flagRef = (const ushort_t*)g1;

    char* base = (char*)d_ws;
    size_t off = 0;
    auto carve = [&](size_t bytes) -> void* {
        void* p = base + off;
        off += (bytes + 255) & ~(size_t)255;
        return p;
    };
    int*      counts = (int*)carve((size_t)N * 4);
    float*    stats  = (float*)carve((size_t)3 * 2 * STAT_SLICES * HH * 4);
    int*      bar    = (int*)carve(256);          // [0]=cnt, [1]=rel
    size_t    zbytes = off;                       // memset range [0, zbytes)
    float*    dis    = (float*)carve((size_t)N * 4);
    int*      rowptr = (int*)carve((size_t)(N + 1) * 4);
    int*      partial= (int*)carve(256 * 4);
    uint2*    erec   = (uint2*)carve((size_t)E * 8);
    ushort_t* Wt1    = (ushort_t*)carve((size_t)128 * 256 * 2);
    ushort_t* Wt2    = (ushort_t*)carve((size_t)128 * 128 * 2);
    ushort_t* Wt3    = (ushort_t*)carve((size_t)128 * 128 * 2);
    ushort_t* tbuf   = (ushort_t*)carve((size_t)N * HH * 2);
    ushort_t* gbuf   = (ushort_t*)carve((size_t)N * HH * 2);
    float*    cvec   = (float*)carve((size_t)1281 * 4);

    const int nbScan = (N + 2047) / 2048;
    const int histB  = (E + 255) / 256;
    const int disB   = (N + 255) / 256;
    const int mm1B   = 1024;

    hipMemsetAsync(d_ws, 0, zbytes, stream);   // counts + stats + barrier

    preK<<<histB + 256 + 1, 256, 0, stream>>>(dst, counts, E, W1, Wt1, W2, Wt2, W3, Wt3,
                                              g1, b1, b2, b3, g2, g3, be1, be2, be3, Wf, bfp,
                                              cvec, histB);
    scanAdisK<<<nbScan + disB, 256, 0, stream>>>(counts, partial, dis, N, nbScan);
    mm1scanCK<<<nbScan + mm1B, 256, 0, stream>>>(x, Wt1, tbuf, N, flagRef,
                                                 counts, partial, rowptr, nbScan);
    fusedK<<<FB, 256, 0, stream>>>(src, dst, rowptr, counts, dis, erec, E,
                                   Wt2, Wt3, tbuf, gbuf, cvec, stats,
                                   d_out, N, flagRef, &bar[0], &bar[1]);
}

// Round 7
// 1121.254 us; speedup vs baseline: 1.0538x; 1.0538x over previous
//
#include <hip/hip_runtime.h>
#include <hip/hip_bf16.h>

typedef unsigned short ushort_t;
typedef __bf16 bf16x8 __attribute__((ext_vector_type(8)));
typedef unsigned short ushort8 __attribute__((ext_vector_type(8)));
typedef unsigned short ushort4v __attribute__((ext_vector_type(4)));
typedef float f32x4 __attribute__((ext_vector_type(4)));

#define HH 128          // hidden dim
#define EPS 1e-5f
#define STAT_SLICES 32
#define MTILE 32        // mm1 tile rows
#define FB 1024         // fused kernel grid: 4 blocks/CU x 256 CU (co-resident by construction)

__device__ __forceinline__ float bf2f(ushort_t u) {
    unsigned v = ((unsigned)u) << 16;
    return __builtin_bit_cast(float, v);
}
__device__ __forceinline__ ushort_t f2bf(float f) {
    unsigned u = __builtin_bit_cast(unsigned, f);
    unsigned r = (u + 0x7fffu + ((u >> 16) & 1u)) >> 16;
    return (ushort_t)r;
}
__device__ __forceinline__ float cvt(const void* p, int i, int flag) {
    return flag ? bf2f(((const ushort_t*)p)[i]) : ((const float*)p)[i];
}
// accumulate 8 bf16 channels (one uint4) scaled by c into a[8]
__device__ __forceinline__ void acc8(const uint4 w, float c, float a[8]) {
    unsigned x0 = w.x, x1 = w.y, x2 = w.z, x3 = w.w;
    a[0] = fmaf(__builtin_bit_cast(float, x0 << 16), c, a[0]);
    a[1] = fmaf(__builtin_bit_cast(float, x0 & 0xffff0000u), c, a[1]);
    a[2] = fmaf(__builtin_bit_cast(float, x1 << 16), c, a[2]);
    a[3] = fmaf(__builtin_bit_cast(float, x1 & 0xffff0000u), c, a[3]);
    a[4] = fmaf(__builtin_bit_cast(float, x2 << 16), c, a[4]);
    a[5] = fmaf(__builtin_bit_cast(float, x2 & 0xffff0000u), c, a[5]);
    a[6] = fmaf(__builtin_bit_cast(float, x3 << 16), c, a[6]);
    a[7] = fmaf(__builtin_bit_cast(float, x3 & 0xffff0000u), c, a[7]);
}

// device-wide barrier: all FB blocks co-resident (enforced via __launch_bounds__+grid).
// Arrival: ONE atomicAdd per block. Wait: acquire-LOAD polling (no RMW -> no exclusive-
// ownership serialization at the coherence point; round-6's atomicAdd(rel,0) polling
// cost ~128us/barrier). cnt and rel live on separate 256B lines.
__device__ __forceinline__ void gridSync(int* cnt, int* rel, int phase, int nb) {
    __syncthreads();
    if (threadIdx.x == 0) {
        __threadfence();                       // release: my phase writes visible
        int prev = atomicAdd(cnt, 1);
        if (prev == nb * phase - 1) {
            __hip_atomic_store(rel, phase, __ATOMIC_RELEASE, __HIP_MEMORY_SCOPE_AGENT);
        } else {
            while (__hip_atomic_load(rel, __ATOMIC_ACQUIRE, __HIP_MEMORY_SCOPE_AGENT) < phase)
                __builtin_amdgcn_s_sleep(2);
        }
        __threadfence();                       // acquire: invalidate stale caches
    }
    __syncthreads();
}

// ================= fused pre-kernel: hist | weight-transpose | setup =================
// Wt stored UNPADDED row-major: Wt1[128][256], Wt2/3[128][128]
__global__ void preK(const int* __restrict__ dst, int* __restrict__ counts, int E,
                     const void* W1, ushort_t* Wt1, const void* W2, ushort_t* Wt2,
                     const void* W3, ushort_t* Wt3,
                     const void* g1, const void* b1, const void* b2, const void* b3,
                     const void* g2, const void* g3, const void* be1, const void* be2,
                     const void* be3, const void* Wfp, const void* bfp,
                     float* __restrict__ cvec, int histB) {
    const int bid = blockIdx.x;
    const int tid = threadIdx.x;
    const int flag = (((const ushort_t*)g1)[0] == 0x3F80) ? 1 : 0;
    if (bid < histB) {
        int e = bid * 256 + tid;
        if (e < E) atomicAdd(&counts[dst[e]], 1);
    } else if (bid < histB + 256) {
        int idx = (bid - histB) * 256 + tid;   // 0..65535
        const void* W; ushort_t* Wt; int K;
        if (idx < 32768)      { W = W1; Wt = Wt1; K = 256; }
        else if (idx < 49152) { W = W2; Wt = Wt2; K = 128; idx -= 32768; }
        else                  { W = W3; Wt = Wt3; K = 128; idx -= 49152; }
        int k = idx >> 7, nn = idx & 127;
        Wt[nn * K + k] = flag ? ((const ushort_t*)W)[idx] : f2bf(((const float*)W)[idx]);
    } else {
        int t = tid;
        if (t < 128) {
            cvec[t]        = cvt(b1, t, flag);
            cvec[128 + t]  = cvt(b2, t, flag);
            cvec[256 + t]  = cvt(b3, t, flag);
            cvec[384 + t]  = cvt(g1, t, flag);
            cvec[512 + t]  = cvt(g2, t, flag);
            cvec[640 + t]  = cvt(g3, t, flag);
            cvec[768 + t]  = cvt(be1, t, flag);
            cvec[896 + t]  = cvt(be2, t, flag);
            cvec[1024 + t] = cvt(be3, t, flag);
            cvec[1152 + t] = cvt(Wfp, t, flag);
            if (t == 0) cvec[1280] = cvt(bfp, 0, flag);
        }
    }
}

// ================= fused: scanA (block sums) | disK =================
__global__ void scanAdisK(const int* __restrict__ cnt, int* __restrict__ partial,
                          float* __restrict__ dis, int n, int nbScan) {
    __shared__ int lds[256];
    const int tid = threadIdx.x;
    if ((int)blockIdx.x < nbScan) {
        int base = blockIdx.x * 2048 + tid * 8;
        int s = 0;
#pragma unroll
        for (int j = 0; j < 8; ++j) { int idx = base + j; if (idx < n) s += cnt[idx]; }
        lds[tid] = s; __syncthreads();
        for (int off = 128; off; off >>= 1) { if (tid < off) lds[tid] += lds[tid + off]; __syncthreads(); }
        if (tid == 0) partial[blockIdx.x] = lds[0];
    } else {
        int i = (blockIdx.x - nbScan) * 256 + tid;
        if (i < n) dis[i] = rsqrtf((float)cnt[i] + 1.0f);
    }
}

// scanC with local recompute of the partial prefix
__device__ __forceinline__ void scanC2Dev(int* lds, const int* __restrict__ cnt,
                                          const int* __restrict__ partial,
                                          int* __restrict__ rowptr, int n, int bid, int nb) {
    const int tid = threadIdx.x;
    int pre = 0, tot = 0;
    for (int i = 0; i < nb; ++i) { int v = partial[i]; if (i < bid) pre += v; tot += v; }
    int base = bid * 2048 + tid * 8;
    int v[8]; int s = 0;
#pragma unroll
    for (int j = 0; j < 8; ++j) { int idx = base + j; v[j] = (idx < n) ? cnt[idx] : 0; s += v[j]; }
    lds[tid] = s; __syncthreads();
    for (int off = 1; off < 256; off <<= 1) {
        int x = (tid >= off) ? lds[tid - off] : 0;
        __syncthreads();
        lds[tid] += x;
        __syncthreads();
    }
    int excl = lds[tid] - s;
    int off0 = pre + excl;
#pragma unroll
    for (int j = 0; j < 8; ++j) {
        int idx = base + j;
        if (idx < n) { rowptr[idx] = off0; off0 += v[j]; }
    }
    if (bid == 0 && tid == 0) rowptr[n] = tot;
}

// ================= mm layer1 (K=256): W in REGISTERS, cooperative bf16 A staging ======
__global__ __launch_bounds__(256) void mm1scanCK(const void* __restrict__ x,
                                                 const ushort_t* __restrict__ Wt1,
                                                 ushort_t* __restrict__ tbuf, int n,
                                                 const ushort_t* __restrict__ flagRef,
                                                 const int* __restrict__ cnt,
                                                 const int* __restrict__ partial,
                                                 int* __restrict__ rowptr, int nbScan) {
    __shared__ char smem[33792];           // 2 x 16KB A bufs | scanC scratch (1KB)
    const int tid = threadIdx.x;
    if ((int)blockIdx.x < nbScan) {
        scanC2Dev((int*)smem, cnt, partial, rowptr, n, blockIdx.x, nbScan);
        return;
    }
    const int arm = blockIdx.x - nbScan;
    const int NB  = gridDim.x - nbScan;
    const int nTiles = (n + MTILE - 1) / MTILE;
    if (arm >= nTiles) return;

    const int lane = tid & 63, wave = tid >> 6;
    const int m = lane & 15, q = lane >> 4;
    const int flag = (flagRef[0] == 0x3F80) ? 1 : 0;

    // ---- W fragments in registers: wave w covers out-ch groups t = 2w, 2w+1
    ushort8 wfrag[8][2];
#pragma unroll
    for (int s = 0; s < 8; ++s)
#pragma unroll
        for (int tt = 0; tt < 2; ++tt)
            wfrag[s][tt] = *(const ushort8*)&Wt1[(size_t)((wave * 2 + tt) * 16 + m) * 256 + s * 32 + q * 8];

    // staging thread mapping: row sr (0..31), 32 cols starting at sa*32
    const int sr = tid >> 3, sa = tid & 7;
    char* buf0 = smem;
    char* buf1 = smem + 16384;

    float4  f[8];
    ushort8 v[4];

    auto stageLoad = [&](int T) {
        int row = T * MTILE + sr; if (row >= n) row = n - 1;
        if (flag) {
            const ushort_t* xp = (const ushort_t*)x + (size_t)row * 256 + sa * 32;
#pragma unroll
            for (int j = 0; j < 4; ++j) v[j] = *(const ushort8*)(xp + j * 8);
        } else {
            const float* xp = (const float*)x + (size_t)row * 256 + sa * 32;
#pragma unroll
            for (int j = 0; j < 8; ++j) f[j] = *(const float4*)(xp + j * 4);
        }
    };
    auto convWrite = [&](char* buf) {
        if (!flag) {
#pragma unroll
            for (int j = 0; j < 4; ++j) {
                float4 a = f[2 * j], b = f[2 * j + 1];
                ushort8 t8;
                t8[0] = f2bf(a.x); t8[1] = f2bf(a.y); t8[2] = f2bf(a.z); t8[3] = f2bf(a.w);
                t8[4] = f2bf(b.x); t8[5] = f2bf(b.y); t8[6] = f2bf(b.z); t8[7] = f2bf(b.w);
                v[j] = t8;
            }
        }
#pragma unroll
        for (int j = 0; j < 4; ++j) {
            int u = (sa * 4 + j) ^ (sr & 7);
            *(ushort8*)(buf + sr * 512 + u * 16) = v[j];
        }
    };
    auto computeStore = [&](int T, const char* buf) {
        f32x4 acc[2][2];
#pragma unroll
        for (int bb = 0; bb < 2; ++bb)
#pragma unroll
            for (int tt = 0; tt < 2; ++tt) acc[bb][tt] = (f32x4){0.f, 0.f, 0.f, 0.f};
#pragma unroll
        for (int bb = 0; bb < 2; ++bb) {
            const char* base = buf + (bb * 16 + m) * 512;
#pragma unroll
            for (int s = 0; s < 8; ++s) {
                ushort8 xf = *(const ushort8*)(base + (((s * 4 + q) ^ (m & 7)) * 16));
                bf16x8 xb = __builtin_bit_cast(bf16x8, xf);
#pragma unroll
                for (int tt = 0; tt < 2; ++tt)
                    acc[bb][tt] = __builtin_amdgcn_mfma_f32_16x16x32_bf16(
                        __builtin_bit_cast(bf16x8, wfrag[s][tt]), xb, acc[bb][tt], 0, 0, 0);
            }
        }
#pragma unroll
        for (int bb = 0; bb < 2; ++bb) {
            int node = T * MTILE + bb * 16 + m;
            if (node < n) {
#pragma unroll
                for (int tt = 0; tt < 2; ++tt) {
                    ushort4v pk;
#pragma unroll
                    for (int r = 0; r < 4; ++r) pk[r] = f2bf(acc[bb][tt][r]);
                    *(ushort4v*)(tbuf + (size_t)node * HH + (wave * 2 + tt) * 16 + q * 4) = pk;
                }
            }
        }
    };

    // prologue
    stageLoad(arm); convWrite(buf0);
    __syncthreads();
    int T = arm, pp = 0;
    while (true) {
        int Tn = T + NB;
        bool more = (Tn < nTiles);
        if (more) stageLoad(Tn);               // issue next-tile loads early
        computeStore(T, pp ? buf1 : buf0);     // hide load latency under MFMAs
        if (!more) break;
        convWrite(pp ? buf0 : buf1);
        __syncthreads();
        T = Tn; pp ^= 1;
    }
}

// ================= fused post-mm1 chain: scatter|agg1|mm2|agg2|mm3|agg3|out ===========
// One kernel, 6 device-wide barriers. 1024 blocks x 256 thr, 4 blocks/CU co-resident
// (launch_bounds caps VGPR at 128; LDS 17.4KB). mm phases: W in regs (32 VGPR),
// reg-staged XOR-swizzled A tiles (2x8KB dbuf).
__global__ __launch_bounds__(256, 4) void fusedK(
        const int* __restrict__ src, const int* __restrict__ dst,
        const int* __restrict__ rowptr, int* __restrict__ fill,
        const float* __restrict__ dis, uint2* __restrict__ erec, int E,
        const ushort_t* __restrict__ Wt2, const ushort_t* __restrict__ Wt3,
        ushort_t* __restrict__ tbuf, ushort_t* __restrict__ gbuf,
        const float* __restrict__ cvec, float* __restrict__ stats,
        void* __restrict__ outv, int n, const ushort_t* __restrict__ flagRef,
        int* __restrict__ bcnt, int* __restrict__ brel) {
    __shared__ char smem[17408];           // mm: 2x8KB A dbuf + 1KB scw | agg: 4KB red
    const int NB  = gridDim.x;
    const int tid = threadIdx.x;
    const int lane = tid & 63, wave = tid >> 6;

    const float* c_b1  = cvec;        const float* c_b2  = cvec + 128;
    const float* c_b3  = cvec + 256;  const float* c_g1  = cvec + 384;
    const float* c_g2  = cvec + 512;  const float* c_g3  = cvec + 640;
    const float* c_be1 = cvec + 768;  const float* c_be2 = cvec + 896;
    const float* c_be3 = cvec + 1024; const float* c_Wf  = cvec + 1152;
    const float* c_bf  = cvec + 1280;
    float* ssum0 = stats;            float* ssq0 = stats + 4096;
    float* ssum1 = stats + 8192;     float* ssq1 = stats + 12288;
    float* ssum2 = stats + 16384;    float* ssq2 = stats + 20480;

    // ---------------- P0: CSR scatter ----------------
    for (int e = blockIdx.x * 256 + tid; e < E; e += NB * 256) {
        int d = dst[e], s = src[e];
        int old = atomicSub(&fill[d], 1);
        int pos = rowptr[d] + old - 1;
        float c = dis[s] * dis[d];
        uint2 r; r.x = (unsigned)s; r.y = __builtin_bit_cast(unsigned, c);
        erec[pos] = r;
    }

    // ---------------- agg phase (t -> g, bias, stats) ----------------
    auto aggPhase = [&](const ushort_t* __restrict__ t, ushort_t* __restrict__ g,
                        const float* __restrict__ bias,
                        float* __restrict__ ssum, float* __restrict__ ssq) {
        const int grp = lane >> 4, p = lane & 15, cb = p * 8;
        float bch[8];
#pragma unroll
        for (int j = 0; j < 8; ++j) bch[j] = bias[cb + j];
        float s[8], q[8];
#pragma unroll
        for (int j = 0; j < 8; ++j) { s[j] = 0.f; q[j] = 0.f; }

        for (int node = blockIdx.x * 16 + wave * 4 + grp; node < n; node += NB * 16) {
            float d = dis[node];
            float d2 = d * d;
            float a[8];
#pragma unroll
            for (int j = 0; j < 8; ++j) a[j] = 0.f;
            uint4 sv = *(const uint4*)(t + (size_t)node * HH + cb);
            acc8(sv, d2, a);

            const int beg = rowptr[node], end = rowptr[node + 1];
            int e = beg;
            for (; e + 8 <= end; e += 8) {
                uint2 rr[8];
#pragma unroll
                for (int kk = 0; kk < 8; ++kk) rr[kk] = erec[e + kk];
                uint4 w0[4];
#pragma unroll
                for (int kk = 0; kk < 4; ++kk)
                    w0[kk] = *(const uint4*)(t + (size_t)rr[kk].x * HH + cb);
                uint4 w1[4];
#pragma unroll
                for (int kk = 0; kk < 4; ++kk)
                    w1[kk] = *(const uint4*)(t + (size_t)rr[4 + kk].x * HH + cb);
#pragma unroll
                for (int kk = 0; kk < 4; ++kk)
                    acc8(w0[kk], __builtin_bit_cast(float, rr[kk].y), a);
#pragma unroll
                for (int kk = 0; kk < 4; ++kk)
                    acc8(w1[kk], __builtin_bit_cast(float, rr[4 + kk].y), a);
            }
            if (e < end) {
                uint2 rr[8];
#pragma unroll
                for (int kk = 0; kk < 8; ++kk) {
                    int idx = e + kk;
                    rr[kk] = (idx < end) ? erec[idx] : (uint2){0u, 0u};
                }
                uint4 w0[4];
#pragma unroll
                for (int kk = 0; kk < 4; ++kk)
                    w0[kk] = *(const uint4*)(t + (size_t)rr[kk].x * HH + cb);
                uint4 w1[4];
#pragma unroll
                for (int kk = 0; kk < 4; ++kk)
                    w1[kk] = *(const uint4*)(t + (size_t)rr[4 + kk].x * HH + cb);
#pragma unroll
                for (int kk = 0; kk < 4; ++kk)
                    acc8(w0[kk], __builtin_bit_cast(float, rr[kk].y), a);
#pragma unroll
                for (int kk = 0; kk < 4; ++kk)
                    acc8(w1[kk], __builtin_bit_cast(float, rr[4 + kk].y), a);
            }

            ushort8 pk;
#pragma unroll
            for (int j = 0; j < 8; ++j) {
                a[j] += bch[j];
                pk[j] = f2bf(a[j]);
                s[j] += a[j]; q[j] += a[j] * a[j];
            }
            *(ushort8*)(g + (size_t)node * HH + cb) = pk;
        }

#pragma unroll
        for (int j = 0; j < 8; ++j) {
            s[j] += __shfl_xor(s[j], 16); s[j] += __shfl_xor(s[j], 32);
            q[j] += __shfl_xor(q[j], 16); q[j] += __shfl_xor(q[j], 32);
        }
        float (*red)[16][16] = (float (*)[16][16])smem;
        __syncthreads();                       // smem free from prior phase
        if (grp == 0) {
#pragma unroll
            for (int j = 0; j < 8; ++j) { red[wave][p][j] = s[j]; red[wave][p][8 + j] = q[j]; }
        }
        __syncthreads();
        {
            int ch = tid & 127, kind = tid >> 7;
            float S = 0.f;
#pragma unroll
            for (int w = 0; w < 4; ++w) S += red[w][ch >> 3][kind * 8 + (ch & 7)];
            int slice = (blockIdx.x & (STAT_SLICES - 1)) * HH;
            atomicAdd((kind ? ssq : ssum) + slice + ch, S);
        }
    };

    // ---------------- mm+BN phase (A -> out, K=128, W in regs) ----------------
    auto mmPhase = [&](const ushort_t* __restrict__ A, const ushort_t* __restrict__ Wt,
                       ushort_t* __restrict__ out,
                       const float* __restrict__ ssum, const float* __restrict__ ssq,
                       const float* __restrict__ gam, const float* __restrict__ bet) {
        float* scw = (float*)(smem + 16384);
        if (tid < 128) {
            float S = 0.f, Q = 0.f;
#pragma unroll
            for (int sl = 0; sl < STAT_SLICES; ++sl) { S += ssum[sl * HH + tid]; Q += ssq[sl * HH + tid]; }
            float invn = 1.0f / (float)n;
            float mu = S * invn;
            float var = fmaxf(Q * invn - mu * mu, 0.f);
            float sc = gam[tid] * rsqrtf(var + EPS);
            scw[tid] = sc;
            scw[128 + tid] = bet[tid] - mu * sc;
        }
        const int m = lane & 15, q4 = lane >> 4;
        ushort8 wfrag[4][2];
#pragma unroll
        for (int s = 0; s < 4; ++s)
#pragma unroll
            for (int tt = 0; tt < 2; ++tt)
                wfrag[s][tt] = *(const ushort8*)&Wt[(size_t)((wave * 2 + tt) * 16 + m) * 128 + s * 32 + q4 * 8];

        const int sr = tid >> 3, sa = tid & 7;   // stage: row sr (0..31), 32B block sa
        char* b0 = smem;
        char* b1 = smem + 8192;
        ushort8 sv[2];

        auto sLoad = [&](int T) {
            int row = T * 32 + sr; if (row >= n) row = n - 1;
            const ushort_t* ap = A + (size_t)row * HH + sa * 16;
            sv[0] = *(const ushort8*)ap;
            sv[1] = *(const ushort8*)(ap + 8);
        };
        auto sWrite = [&](char* buf) {
#pragma unroll
            for (int j = 0; j < 2; ++j) {
                int u = (sa * 2 + j) ^ (sr & 7);
                *(ushort8*)(buf + sr * 256 + u * 16) = sv[j];
            }
        };
        auto comp = [&](int T, const char* buf) {
            f32x4 acc[2][2];
#pragma unroll
            for (int bb = 0; bb < 2; ++bb)
#pragma unroll
                for (int tt = 0; tt < 2; ++tt) acc[bb][tt] = (f32x4){0.f, 0.f, 0.f, 0.f};
#pragma unroll
            for (int bb = 0; bb < 2; ++bb) {
                const char* arow = buf + (bb * 16 + m) * 256;
#pragma unroll
                for (int s = 0; s < 4; ++s) {
                    ushort8 av = *(const ushort8*)(arow + (((s * 4 + q4) ^ (m & 7)) * 16));
                    int kb = s * 32 + q4 * 8;
#pragma unroll
                    for (int j = 0; j < 8; ++j)
                        av[j] = f2bf(fmaxf(bf2f(av[j]) * scw[kb + j] + scw[128 + kb + j], 0.f));
                    bf16x8 nf = __builtin_bit_cast(bf16x8, av);
#pragma unroll
                    for (int tt = 0; tt < 2; ++tt)
                        acc[bb][tt] = __builtin_amdgcn_mfma_f32_16x16x32_bf16(
                            __builtin_bit_cast(bf16x8, wfrag[s][tt]), nf, acc[bb][tt], 0, 0, 0);
                }
            }
#pragma unroll
            for (int bb = 0; bb < 2; ++bb) {
                int node = T * 32 + bb * 16 + m;
                if (node < n) {
#pragma unroll
                    for (int tt = 0; tt < 2; ++tt) {
                        ushort4v pk;
#pragma unroll
                        for (int r = 0; r < 4; ++r) pk[r] = f2bf(acc[bb][tt][r]);
                        *(ushort4v*)(out + (size_t)node * HH + (wave * 2 + tt) * 16 + q4 * 4) = pk;
                    }
                }
            }
        };

        const int nT = (n + 31) >> 5;
        int T = blockIdx.x, pp = 0;
        if (T < nT) sLoad(T);
        __syncthreads();                       // scw ready; smem free from prior phase
        if (T < nT) sWrite(b0);
        __syncthreads();
        while (T < nT) {
            int Tn = T + NB;
            if (Tn < nT) sLoad(Tn);
            comp(T, pp ? b1 : b0);
            if (Tn >= nT) break;
            sWrite(pp ? b0 : b1);
            __syncthreads();
            T = Tn; pp ^= 1;
        }
    };

    // ---------------- phase chain ----------------
    gridSync(bcnt, brel, 1, NB);
    aggPhase(tbuf, gbuf, c_b1, ssum0, ssq0);
    gridSync(bcnt, brel, 2, NB);
    mmPhase(gbuf, Wt2, tbuf, ssum0, ssq0, c_g1, c_be1);
    gridSync(bcnt, brel, 3, NB);
    aggPhase(tbuf, gbuf, c_b2, ssum1, ssq1);
    gridSync(bcnt, brel, 4, NB);
    mmPhase(gbuf, Wt3, tbuf, ssum1, ssq1, c_g2, c_be2);
    gridSync(bcnt, brel, 5, NB);
    aggPhase(tbuf, gbuf, c_b3, ssum2, ssq2);
    gridSync(bcnt, brel, 6, NB);

    // ---------------- P6: output head ----------------
    {
        float* scw = (float*)(smem + 16384);
        if (tid < 128) {
            float S = 0.f, Q = 0.f;
#pragma unroll
            for (int sl = 0; sl < STAT_SLICES; ++sl) { S += ssum2[sl * HH + tid]; Q += ssq2[sl * HH + tid]; }
            float invn = 1.0f / (float)n;
            float mu = S * invn;
            float var = fmaxf(Q * invn - mu * mu, 0.f);
            float sc = c_g3[tid] * rsqrtf(var + EPS);
            scw[tid] = sc;
            scw[128 + tid] = c_be3[tid] - mu * sc;
        }
        __syncthreads();

        const int grp = lane >> 4, p = lane & 15, cb = p * 8;
        float w8[8], sc8[8], sh8[8];
#pragma unroll
        for (int j = 0; j < 8; ++j) {
            w8[j] = c_Wf[cb + j]; sc8[j] = scw[cb + j]; sh8[j] = scw[128 + cb + j];
        }
        const float bb = c_bf[0];
        const int flag = (flagRef[0] == 0x3F80) ? 1 : 0;

        for (int node = blockIdx.x * 16 + wave * 4 + grp; node < n; node += NB * 16) {
            uint4 v = *(const uint4*)(gbuf + (size_t)node * HH + cb);
            unsigned u[4] = {v.x, v.y, v.z, v.w};
            float x = 0.f;
#pragma unroll
            for (int j = 0; j < 4; ++j) {
                float f0 = __builtin_bit_cast(float, u[j] << 16);
                float f1 = __builtin_bit_cast(float, u[j] & 0xffff0000u);
                x += fmaxf(f0 * sc8[2 * j] + sh8[2 * j], 0.f) * w8[2 * j];
                x += fmaxf(f1 * sc8[2 * j + 1] + sh8[2 * j + 1], 0.f) * w8[2 * j + 1];
            }
#pragma unroll
            for (int off = 8; off; off >>= 1) x += __shfl_xor(x, off);
            if (p == 0) {
                float r = x + bb;
                if (flag) ((ushort_t*)outv)[node] = f2bf(r);
                else      ((float*)outv)[node] = r;
            }
        }
    }
}

// ================= launch =================
extern "C" void kernel_launch(void* const* d_in, const int* in_sizes, int n_in,
                              void* d_out, int out_size, void* d_ws, size_t ws_size,
                              hipStream_t stream) {
    const int DIN = 256;
    const int N = in_sizes[0] / DIN;
    const int E = in_sizes[1];

    const void* x   = d_in[0];
    const int*  src = (const int*)d_in[1];
    const int*  dst = (const int*)d_in[2];
    const void* W1  = d_in[3];
    const void* b1  = d_in[4];
    const void* g1  = d_in[5];
    const void* be1 = d_in[6];
    const void* W2  = d_in[7];
    const void* b2  = d_in[8];
    const void* g2  = d_in[9];
    const void* be2 = d_in[10];
    const void* W3  = d_in[11];
    const void* b3  = d_in[12];
    const void* g3  = d_in[13];
    const void* be3 = d_in[14];
    const void* Wf  = d_in[15];
    const void* bfp = d_in[16];
    const ushort_t* flagRef = (const ushort_t*)g1;

    char* base = (char*)d_ws;
    size_t off = 0;
    auto carve = [&](size_t bytes) -> void* {
        void* p = base + off;
        off += (bytes + 255) & ~(size_t)255;
        return p;
    };
    int*      counts = (int*)carve((size_t)N * 4);
    float*    stats  = (float*)carve((size_t)3 * 2 * STAT_SLICES * HH * 4);
    int*      bar    = (int*)carve(512);          // [0]=cnt, [64]=rel (separate 256B lines)
    size_t    zbytes = off;                       // memset range [0, zbytes)
    float*    dis    = (float*)carve((size_t)N * 4);
    int*      rowptr = (int*)carve((size_t)(N + 1) * 4);
    int*      partial= (int*)carve(256 * 4);
    uint2*    erec   = (uint2*)carve((size_t)E * 8);
    ushort_t* Wt1    = (ushort_t*)carve((size_t)128 * 256 * 2);
    ushort_t* Wt2    = (ushort_t*)carve((size_t)128 * 128 * 2);
    ushort_t* Wt3    = (ushort_t*)carve((size_t)128 * 128 * 2);
    ushort_t* tbuf   = (ushort_t*)carve((size_t)N * HH * 2);
    ushort_t* gbuf   = (ushort_t*)carve((size_t)N * HH * 2);
    float*    cvec   = (float*)carve((size_t)1281 * 4);

    const int nbScan = (N + 2047) / 2048;
    const int histB  = (E + 255) / 256;
    const int disB   = (N + 255) / 256;
    const int mm1B   = 1024;

    hipMemsetAsync(d_ws, 0, zbytes, stream);   // counts + stats + barrier

    preK<<<histB + 256 + 1, 256, 0, stream>>>(dst, counts, E, W1, Wt1, W2, Wt2, W3, Wt3,
                                              g1, b1, b2, b3, g2, g3, be1, be2, be3, Wf, bfp,
                                              cvec, histB);
    scanAdisK<<<nbScan + disB, 256, 0, stream>>>(counts, partial, dis, N, nbScan);
    mm1scanCK<<<nbScan + mm1B, 256, 0, stream>>>(x, Wt1, tbuf, N, flagRef,
                                                 counts, partial, rowptr, nbScan);
    fusedK<<<FB, 256, 0, stream>>>(src, dst, rowptr, counts, dis, erec, E,
                                   Wt2, Wt3, tbuf, gbuf, cvec, stats,
                                   d_out, N, flagRef, &bar[0], &bar[64]);
}

// Round 8
// 760.458 us; speedup vs baseline: 1.5537x; 1.4744x over previous
//
#include <hip/hip_runtime.h>
#include <hip/hip_bf16.h>

typedef unsigned short ushort_t;
typedef __bf16 bf16x8 __attribute__((ext_vector_type(8)));
typedef unsigned short ushort8 __attribute__((ext_vector_type(8)));
typedef unsigned short ushort4v __attribute__((ext_vector_type(4)));
typedef float f32x4 __attribute__((ext_vector_type(4)));

#define HH 128          // hidden dim
#define EPS 1e-5f
#define STAT_SLICES 32
#define MTILE 32        // mm1 tile rows
#define FB 1024         // fused kernel grid: 4 blocks/CU x 256 CU (co-resident by construction)
#define BAR_LINES 32    // hierarchical barrier arrival lines (FB % BAR_LINES == 0)

__device__ __forceinline__ float bf2f(ushort_t u) {
    unsigned v = ((unsigned)u) << 16;
    return __builtin_bit_cast(float, v);
}
__device__ __forceinline__ ushort_t f2bf(float f) {
    unsigned u = __builtin_bit_cast(unsigned, f);
    unsigned r = (u + 0x7fffu + ((u >> 16) & 1u)) >> 16;
    return (ushort_t)r;
}
__device__ __forceinline__ float cvt(const void* p, int i, int flag) {
    return flag ? bf2f(((const ushort_t*)p)[i]) : ((const float*)p)[i];
}
// accumulate 8 bf16 channels (one uint4) scaled by c into a[8]
__device__ __forceinline__ void acc8(const uint4 w, float c, float a[8]) {
    unsigned x0 = w.x, x1 = w.y, x2 = w.z, x3 = w.w;
    a[0] = fmaf(__builtin_bit_cast(float, x0 << 16), c, a[0]);
    a[1] = fmaf(__builtin_bit_cast(float, x0 & 0xffff0000u), c, a[1]);
    a[2] = fmaf(__builtin_bit_cast(float, x1 << 16), c, a[2]);
    a[3] = fmaf(__builtin_bit_cast(float, x1 & 0xffff0000u), c, a[3]);
    a[4] = fmaf(__builtin_bit_cast(float, x2 << 16), c, a[4]);
    a[5] = fmaf(__builtin_bit_cast(float, x2 & 0xffff0000u), c, a[5]);
    a[6] = fmaf(__builtin_bit_cast(float, x3 << 16), c, a[6]);
    a[7] = fmaf(__builtin_bit_cast(float, x3 & 0xffff0000u), c, a[7]);
}

// device-wide barrier, hierarchical arrival:
//  - 1024 blocks -> 32 counter lines (256B apart): 32-way-parallel arrival, ~32
//    serialized device atomics per line (vs 1024 on one line in r6/r7 = ~15-20us).
//  - line-finishers (32) add to mid counter; last stores release epoch.
//  - waiters poll with RELAXED agent loads (no per-poll cache invalidate; r7's
//    acquire-poll emitted buffer_inv each iteration) + ONE acquire fence at exit.
__device__ __forceinline__ void gridSync(int* lines, int* mid, int* rel, int phase, int nb) {
    __syncthreads();
    if (threadIdx.x == 0) {
        __threadfence();                       // release: my phase writes visible
        const int per = nb / BAR_LINES;
        int* lp = lines + (blockIdx.x & (BAR_LINES - 1)) * 64;
        int prev = atomicAdd(lp, 1);
        if (prev == per * phase - 1) {
            int pm = atomicAdd(mid, 1);
            if (pm == BAR_LINES * phase - 1)
                __hip_atomic_store(rel, phase, __ATOMIC_RELEASE, __HIP_MEMORY_SCOPE_AGENT);
        }
        while (__hip_atomic_load(rel, __ATOMIC_RELAXED, __HIP_MEMORY_SCOPE_AGENT) < phase)
            __builtin_amdgcn_s_sleep(4);
        __threadfence();                       // acquire: invalidate stale caches ONCE
    }
    __syncthreads();
}

// ================= fused pre-kernel: hist | weight-transpose | setup =================
// Wt stored UNPADDED row-major: Wt1[128][256], Wt2/3[128][128]
__global__ void preK(const int* __restrict__ dst, int* __restrict__ counts, int E,
                     const void* W1, ushort_t* Wt1, const void* W2, ushort_t* Wt2,
                     const void* W3, ushort_t* Wt3,
                     const void* g1, const void* b1, const void* b2, const void* b3,
                     const void* g2, const void* g3, const void* be1, const void* be2,
                     const void* be3, const void* Wfp, const void* bfp,
                     float* __restrict__ cvec, int histB) {
    const int bid = blockIdx.x;
    const int tid = threadIdx.x;
    const int flag = (((const ushort_t*)g1)[0] == 0x3F80) ? 1 : 0;
    if (bid < histB) {
        int e = bid * 256 + tid;
        if (e < E) atomicAdd(&counts[dst[e]], 1);
    } else if (bid < histB + 256) {
        int idx = (bid - histB) * 256 + tid;   // 0..65535
        const void* W; ushort_t* Wt; int K;
        if (idx < 32768)      { W = W1; Wt = Wt1; K = 256; }
        else if (idx < 49152) { W = W2; Wt = Wt2; K = 128; idx -= 32768; }
        else                  { W = W3; Wt = Wt3; K = 128; idx -= 49152; }
        int k = idx >> 7, nn = idx & 127;
        Wt[nn * K + k] = flag ? ((const ushort_t*)W)[idx] : f2bf(((const float*)W)[idx]);
    } else {
        int t = tid;
        if (t < 128) {
            cvec[t]        = cvt(b1, t, flag);
            cvec[128 + t]  = cvt(b2, t, flag);
            cvec[256 + t]  = cvt(b3, t, flag);
            cvec[384 + t]  = cvt(g1, t, flag);
            cvec[512 + t]  = cvt(g2, t, flag);
            cvec[640 + t]  = cvt(g3, t, flag);
            cvec[768 + t]  = cvt(be1, t, flag);
            cvec[896 + t]  = cvt(be2, t, flag);
            cvec[1024 + t] = cvt(be3, t, flag);
            cvec[1152 + t] = cvt(Wfp, t, flag);
            if (t == 0) cvec[1280] = cvt(bfp, 0, flag);
        }
    }
}

// ================= fused: scanA (block sums) | disK =================
__global__ void scanAdisK(const int* __restrict__ cnt, int* __restrict__ partial,
                          float* __restrict__ dis, int n, int nbScan) {
    __shared__ int lds[256];
    const int tid = threadIdx.x;
    if ((int)blockIdx.x < nbScan) {
        int base = blockIdx.x * 2048 + tid * 8;
        int s = 0;
#pragma unroll
        for (int j = 0; j < 8; ++j) { int idx = base + j; if (idx < n) s += cnt[idx]; }
        lds[tid] = s; __syncthreads();
        for (int off = 128; off; off >>= 1) { if (tid < off) lds[tid] += lds[tid + off]; __syncthreads(); }
        if (tid == 0) partial[blockIdx.x] = lds[0];
    } else {
        int i = (blockIdx.x - nbScan) * 256 + tid;
        if (i < n) dis[i] = rsqrtf((float)cnt[i] + 1.0f);
    }
}

// scanC with local recompute of the partial prefix
__device__ __forceinline__ void scanC2Dev(int* lds, const int* __restrict__ cnt,
                                          const int* __restrict__ partial,
                                          int* __restrict__ rowptr, int n, int bid, int nb) {
    const int tid = threadIdx.x;
    int pre = 0, tot = 0;
    for (int i = 0; i < nb; ++i) { int v = partial[i]; if (i < bid) pre += v; tot += v; }
    int base = bid * 2048 + tid * 8;
    int v[8]; int s = 0;
#pragma unroll
    for (int j = 0; j < 8; ++j) { int idx = base + j; v[j] = (idx < n) ? cnt[idx] : 0; s += v[j]; }
    lds[tid] = s; __syncthreads();
    for (int off = 1; off < 256; off <<= 1) {
        int x = (tid >= off) ? lds[tid - off] : 0;
        __syncthreads();
        lds[tid] += x;
        __syncthreads();
    }
    int excl = lds[tid] - s;
    int off0 = pre + excl;
#pragma unroll
    for (int j = 0; j < 8; ++j) {
        int idx = base + j;
        if (idx < n) { rowptr[idx] = off0; off0 += v[j]; }
    }
    if (bid == 0 && tid == 0) rowptr[n] = tot;
}

// ================= mm layer1 (K=256): W in REGISTERS, cooperative bf16 A staging ======
__global__ __launch_bounds__(256) void mm1scanCK(const void* __restrict__ x,
                                                 const ushort_t* __restrict__ Wt1,
                                                 ushort_t* __restrict__ tbuf, int n,
                                                 const ushort_t* __restrict__ flagRef,
                                                 const int* __restrict__ cnt,
                                                 const int* __restrict__ partial,
                                                 int* __restrict__ rowptr, int nbScan) {
    __shared__ char smem[33792];           // 2 x 16KB A bufs | scanC scratch (1KB)
    const int tid = threadIdx.x;
    if ((int)blockIdx.x < nbScan) {
        scanC2Dev((int*)smem, cnt, partial, rowptr, n, blockIdx.x, nbScan);
        return;
    }
    const int arm = blockIdx.x - nbScan;
    const int NB  = gridDim.x - nbScan;
    const int nTiles = (n + MTILE - 1) / MTILE;
    if (arm >= nTiles) return;

    const int lane = tid & 63, wave = tid >> 6;
    const int m = lane & 15, q = lane >> 4;
    const int flag = (flagRef[0] == 0x3F80) ? 1 : 0;

    // ---- W fragments in registers: wave w covers out-ch groups t = 2w, 2w+1
    ushort8 wfrag[8][2];
#pragma unroll
    for (int s = 0; s < 8; ++s)
#pragma unroll
        for (int tt = 0; tt < 2; ++tt)
            wfrag[s][tt] = *(const ushort8*)&Wt1[(size_t)((wave * 2 + tt) * 16 + m) * 256 + s * 32 + q * 8];

    // staging thread mapping: row sr (0..31), 32 cols starting at sa*32
    const int sr = tid >> 3, sa = tid & 7;
    char* buf0 = smem;
    char* buf1 = smem + 16384;

    float4  f[8];
    ushort8 v[4];

    auto stageLoad = [&](int T) {
        int row = T * MTILE + sr; if (row >= n) row = n - 1;
        if (flag) {
            const ushort_t* xp = (const ushort_t*)x + (size_t)row * 256 + sa * 32;
#pragma unroll
            for (int j = 0; j < 4; ++j) v[j] = *(const ushort8*)(xp + j * 8);
        } else {
            const float* xp = (const float*)x + (size_t)row * 256 + sa * 32;
#pragma unroll
            for (int j = 0; j < 8; ++j) f[j] = *(const float4*)(xp + j * 4);
        }
    };
    auto convWrite = [&](char* buf) {
        if (!flag) {
#pragma unroll
            for (int j = 0; j < 4; ++j) {
                float4 a = f[2 * j], b = f[2 * j + 1];
                ushort8 t8;
                t8[0] = f2bf(a.x); t8[1] = f2bf(a.y); t8[2] = f2bf(a.z); t8[3] = f2bf(a.w);
                t8[4] = f2bf(b.x); t8[5] = f2bf(b.y); t8[6] = f2bf(b.z); t8[7] = f2bf(b.w);
                v[j] = t8;
            }
        }
#pragma unroll
        for (int j = 0; j < 4; ++j) {
            int u = (sa * 4 + j) ^ (sr & 7);
            *(ushort8*)(buf + sr * 512 + u * 16) = v[j];
        }
    };
    auto computeStore = [&](int T, const char* buf) {
        f32x4 acc[2][2];
#pragma unroll
        for (int bb = 0; bb < 2; ++bb)
#pragma unroll
            for (int tt = 0; tt < 2; ++tt) acc[bb][tt] = (f32x4){0.f, 0.f, 0.f, 0.f};
#pragma unroll
        for (int bb = 0; bb < 2; ++bb) {
            const char* base = buf + (bb * 16 + m) * 512;
#pragma unroll
            for (int s = 0; s < 8; ++s) {
                ushort8 xf = *(const ushort8*)(base + (((s * 4 + q) ^ (m & 7)) * 16));
                bf16x8 xb = __builtin_bit_cast(bf16x8, xf);
#pragma unroll
                for (int tt = 0; tt < 2; ++tt)
                    acc[bb][tt] = __builtin_amdgcn_mfma_f32_16x16x32_bf16(
                        __builtin_bit_cast(bf16x8, wfrag[s][tt]), xb, acc[bb][tt], 0, 0, 0);
            }
        }
#pragma unroll
        for (int bb = 0; bb < 2; ++bb) {
            int node = T * MTILE + bb * 16 + m;
            if (node < n) {
#pragma unroll
                for (int tt = 0; tt < 2; ++tt) {
                    ushort4v pk;
#pragma unroll
                    for (int r = 0; r < 4; ++r) pk[r] = f2bf(acc[bb][tt][r]);
                    *(ushort4v*)(tbuf + (size_t)node * HH + (wave * 2 + tt) * 16 + q * 4) = pk;
                }
            }
        }
    };

    // prologue
    stageLoad(arm); convWrite(buf0);
    __syncthreads();
    int T = arm, pp = 0;
    while (true) {
        int Tn = T + NB;
        bool more = (Tn < nTiles);
        if (more) stageLoad(Tn);               // issue next-tile loads early
        computeStore(T, pp ? buf1 : buf0);     // hide load latency under MFMAs
        if (!more) break;
        convWrite(pp ? buf0 : buf1);
        __syncthreads();
        T = Tn; pp ^= 1;
    }
}

// ================= fused post-mm1 chain: scatter|agg1|mm2|agg2|mm3|agg3|out ===========
// One kernel, 6 device-wide barriers. 1024 blocks x 256 thr, 4 blocks/CU co-resident
// (launch_bounds caps VGPR at 128; LDS 17.4KB). mm phases: W in regs (32 VGPR),
// reg-staged XOR-swizzled A tiles (2x8KB dbuf).
__global__ __launch_bounds__(256, 4) void fusedK(
        const int* __restrict__ src, const int* __restrict__ dst,
        const int* __restrict__ rowptr, int* __restrict__ fill,
        const float* __restrict__ dis, uint2* __restrict__ erec, int E,
        const ushort_t* __restrict__ Wt2, const ushort_t* __restrict__ Wt3,
        ushort_t* __restrict__ tbuf, ushort_t* __restrict__ gbuf,
        const float* __restrict__ cvec, float* __restrict__ stats,
        void* __restrict__ outv, int n, const ushort_t* __restrict__ flagRef,
        int* __restrict__ blines, int* __restrict__ bmid, int* __restrict__ brel) {
    __shared__ char smem[17408];           // mm: 2x8KB A dbuf + 1KB scw | agg: 4KB red
    const int NB  = gridDim.x;
    const int tid = threadIdx.x;
    const int lane = tid & 63, wave = tid >> 6;

    const float* c_b1  = cvec;        const float* c_b2  = cvec + 128;
    const float* c_b3  = cvec + 256;  const float* c_g1  = cvec + 384;
    const float* c_g2  = cvec + 512;  const float* c_g3  = cvec + 640;
    const float* c_be1 = cvec + 768;  const float* c_be2 = cvec + 896;
    const float* c_be3 = cvec + 1024; const float* c_Wf  = cvec + 1152;
    const float* c_bf  = cvec + 1280;
    float* ssum0 = stats;            float* ssq0 = stats + 4096;
    float* ssum1 = stats + 8192;     float* ssq1 = stats + 12288;
    float* ssum2 = stats + 16384;    float* ssq2 = stats + 20480;

    // ---------------- P0: CSR scatter ----------------
    for (int e = blockIdx.x * 256 + tid; e < E; e += NB * 256) {
        int d = dst[e], s = src[e];
        int old = atomicSub(&fill[d], 1);
        int pos = rowptr[d] + old - 1;
        float c = dis[s] * dis[d];
        uint2 r; r.x = (unsigned)s; r.y = __builtin_bit_cast(unsigned, c);
        erec[pos] = r;
    }

    // ---------------- agg phase (t -> g, bias, stats) ----------------
    auto aggPhase = [&](const ushort_t* __restrict__ t, ushort_t* __restrict__ g,
                        const float* __restrict__ bias,
                        float* __restrict__ ssum, float* __restrict__ ssq) {
        const int grp = lane >> 4, p = lane & 15, cb = p * 8;
        float bch[8];
#pragma unroll
        for (int j = 0; j < 8; ++j) bch[j] = bias[cb + j];
        float s[8], q[8];
#pragma unroll
        for (int j = 0; j < 8; ++j) { s[j] = 0.f; q[j] = 0.f; }

        for (int node = blockIdx.x * 16 + wave * 4 + grp; node < n; node += NB * 16) {
            float d = dis[node];
            float d2 = d * d;
            float a[8];
#pragma unroll
            for (int j = 0; j < 8; ++j) a[j] = 0.f;
            uint4 sv = *(const uint4*)(t + (size_t)node * HH + cb);
            acc8(sv, d2, a);

            const int beg = rowptr[node], end = rowptr[node + 1];
            int e = beg;
            for (; e + 8 <= end; e += 8) {
                uint2 rr[8];
#pragma unroll
                for (int kk = 0; kk < 8; ++kk) rr[kk] = erec[e + kk];
                uint4 w0[4];
#pragma unroll
                for (int kk = 0; kk < 4; ++kk)
                    w0[kk] = *(const uint4*)(t + (size_t)rr[kk].x * HH + cb);
                uint4 w1[4];
#pragma unroll
                for (int kk = 0; kk < 4; ++kk)
                    w1[kk] = *(const uint4*)(t + (size_t)rr[4 + kk].x * HH + cb);
#pragma unroll
                for (int kk = 0; kk < 4; ++kk)
                    acc8(w0[kk], __builtin_bit_cast(float, rr[kk].y), a);
#pragma unroll
                for (int kk = 0; kk < 4; ++kk)
                    acc8(w1[kk], __builtin_bit_cast(float, rr[4 + kk].y), a);
            }
            if (e < end) {
                uint2 rr[8];
#pragma unroll
                for (int kk = 0; kk < 8; ++kk) {
                    int idx = e + kk;
                    rr[kk] = (idx < end) ? erec[idx] : (uint2){0u, 0u};
                }
                uint4 w0[4];
#pragma unroll
                for (int kk = 0; kk < 4; ++kk)
                    w0[kk] = *(const uint4*)(t + (size_t)rr[kk].x * HH + cb);
                uint4 w1[4];
#pragma unroll
                for (int kk = 0; kk < 4; ++kk)
                    w1[kk] = *(const uint4*)(t + (size_t)rr[4 + kk].x * HH + cb);
#pragma unroll
                for (int kk = 0; kk < 4; ++kk)
                    acc8(w0[kk], __builtin_bit_cast(float, rr[kk].y), a);
#pragma unroll
                for (int kk = 0; kk < 4; ++kk)
                    acc8(w1[kk], __builtin_bit_cast(float, rr[4 + kk].y), a);
            }

            ushort8 pk;
#pragma unroll
            for (int j = 0; j < 8; ++j) {
                a[j] += bch[j];
                pk[j] = f2bf(a[j]);
                s[j] += a[j]; q[j] += a[j] * a[j];
            }
            *(ushort8*)(g + (size_t)node * HH + cb) = pk;
        }

#pragma unroll
        for (int j = 0; j < 8; ++j) {
            s[j] += __shfl_xor(s[j], 16); s[j] += __shfl_xor(s[j], 32);
            q[j] += __shfl_xor(q[j], 16); q[j] += __shfl_xor(q[j], 32);
        }
        float (*red)[16][16] = (float (*)[16][16])smem;
        __syncthreads();                       // smem free from prior phase
        if (grp == 0) {
#pragma unroll
            for (int j = 0; j < 8; ++j) { red[wave][p][j] = s[j]; red[wave][p][8 + j] = q[j]; }
        }
        __syncthreads();
        {
            int ch = tid & 127, kind = tid >> 7;
            float S = 0.f;
#pragma unroll
            for (int w = 0; w < 4; ++w) S += red[w][ch >> 3][kind * 8 + (ch & 7)];
            int slice = (blockIdx.x & (STAT_SLICES - 1)) * HH;
            atomicAdd((kind ? ssq : ssum) + slice + ch, S);
        }
    };

    // ---------------- mm+BN phase (A -> out, K=128, W in regs) ----------------
    auto mmPhase = [&](const ushort_t* __restrict__ A, const ushort_t* __restrict__ Wt,
                       ushort_t* __restrict__ out,
                       const float* __restrict__ ssum, const float* __restrict__ ssq,
                       const float* __restrict__ gam, const float* __restrict__ bet) {
        float* scw = (float*)(smem + 16384);
        if (tid < 128) {
            float S = 0.f, Q = 0.f;
#pragma unroll
            for (int sl = 0; sl < STAT_SLICES; ++sl) { S += ssum[sl * HH + tid]; Q += ssq[sl * HH + tid]; }
            float invn = 1.0f / (float)n;
            float mu = S * invn;
            float var = fmaxf(Q * invn - mu * mu, 0.f);
            float sc = gam[tid] * rsqrtf(var + EPS);
            scw[tid] = sc;
            scw[128 + tid] = bet[tid] - mu * sc;
        }
        const int m = lane & 15, q4 = lane >> 4;
        ushort8 wfrag[4][2];
#pragma unroll
        for (int s = 0; s < 4; ++s)
#pragma unroll
            for (int tt = 0; tt < 2; ++tt)
                wfrag[s][tt] = *(const ushort8*)&Wt[(size_t)((wave * 2 + tt) * 16 + m) * 128 + s * 32 + q4 * 8];

        const int sr = tid >> 3, sa = tid & 7;   // stage: row sr (0..31), 32B block sa
        char* b0 = smem;
        char* b1 = smem + 8192;
        ushort8 sv[2];

        auto sLoad = [&](int T) {
            int row = T * 32 + sr; if (row >= n) row = n - 1;
            const ushort_t* ap = A + (size_t)row * HH + sa * 16;
            sv[0] = *(const ushort8*)ap;
            sv[1] = *(const ushort8*)(ap + 8);
        };
        auto sWrite = [&](char* buf) {
#pragma unroll
            for (int j = 0; j < 2; ++j) {
                int u = (sa * 2 + j) ^ (sr & 7);
                *(ushort8*)(buf + sr * 256 + u * 16) = sv[j];
            }
        };
        auto comp = [&](int T, const char* buf) {
            f32x4 acc[2][2];
#pragma unroll
            for (int bb = 0; bb < 2; ++bb)
#pragma unroll
                for (int tt = 0; tt < 2; ++tt) acc[bb][tt] = (f32x4){0.f, 0.f, 0.f, 0.f};
#pragma unroll
            for (int bb = 0; bb < 2; ++bb) {
                const char* arow = buf + (bb * 16 + m) * 256;
#pragma unroll
                for (int s = 0; s < 4; ++s) {
                    ushort8 av = *(const ushort8*)(arow + (((s * 4 + q4) ^ (m & 7)) * 16));
                    int kb = s * 32 + q4 * 8;
#pragma unroll
                    for (int j = 0; j < 8; ++j)
                        av[j] = f2bf(fmaxf(bf2f(av[j]) * scw[kb + j] + scw[128 + kb + j], 0.f));
                    bf16x8 nf = __builtin_bit_cast(bf16x8, av);
#pragma unroll
                    for (int tt = 0; tt < 2; ++tt)
                        acc[bb][tt] = __builtin_amdgcn_mfma_f32_16x16x32_bf16(
                            __builtin_bit_cast(bf16x8, wfrag[s][tt]), nf, acc[bb][tt], 0, 0, 0);
                }
            }
#pragma unroll
            for (int bb = 0; bb < 2; ++bb) {
                int node = T * 32 + bb * 16 + m;
                if (node < n) {
#pragma unroll
                    for (int tt = 0; tt < 2; ++tt) {
                        ushort4v pk;
#pragma unroll
                        for (int r = 0; r < 4; ++r) pk[r] = f2bf(acc[bb][tt][r]);
                        *(ushort4v*)(out + (size_t)node * HH + (wave * 2 + tt) * 16 + q4 * 4) = pk;
                    }
                }
            }
        };

        const int nT = (n + 31) >> 5;
        int T = blockIdx.x, pp = 0;
        if (T < nT) sLoad(T);
        __syncthreads();                       // scw ready; smem free from prior phase
        if (T < nT) sWrite(b0);
        __syncthreads();
        while (T < nT) {
            int Tn = T + NB;
            if (Tn < nT) sLoad(Tn);
            comp(T, pp ? b1 : b0);
            if (Tn >= nT) break;
            sWrite(pp ? b0 : b1);
            __syncthreads();
            T = Tn; pp ^= 1;
        }
    };

    // ---------------- phase chain ----------------
    gridSync(blines, bmid, brel, 1, NB);
    aggPhase(tbuf, gbuf, c_b1, ssum0, ssq0);
    gridSync(blines, bmid, brel, 2, NB);
    mmPhase(gbuf, Wt2, tbuf, ssum0, ssq0, c_g1, c_be1);
    gridSync(blines, bmid, brel, 3, NB);
    aggPhase(tbuf, gbuf, c_b2, ssum1, ssq1);
    gridSync(blines, bmid, brel, 4, NB);
    mmPhase(gbuf, Wt3, tbuf, ssum1, ssq1, c_g2, c_be2);
    gridSync(blines, bmid, brel, 5, NB);
    aggPhase(tbuf, gbuf, c_b3, ssum2, ssq2);
    gridSync(blines, bmid, brel, 6, NB);

    // ---------------- P6: output head ----------------
    {
        float* scw = (float*)(smem + 16384);
        if (tid < 128) {
            float S = 0.f, Q = 0.f;
#pragma unroll
            for (int sl = 0; sl < STAT_SLICES; ++sl) { S += ssum2[sl * HH + tid]; Q += ssq2[sl * HH + tid]; }
            float invn = 1.0f / (float)n;
            float mu = S * invn;
            float var = fmaxf(Q * invn - mu * mu, 0.f);
            float sc = c_g3[tid] * rsqrtf(var + EPS);
            scw[tid] = sc;
            scw[128 + tid] = c_be3[tid] - mu * sc;
        }
        __syncthreads();

        const int grp = lane >> 4, p = lane & 15, cb = p * 8;
        float w8[8], sc8[8], sh8[8];
#pragma unroll
        for (int j = 0; j < 8; ++j) {
            w8[j] = c_Wf[cb + j]; sc8[j] = scw[cb + j]; sh8[j] = scw[128 + cb + j];
        }
        const float bb = c_bf[0];
        const int flag = (flagRef[0] == 0x3F80) ? 1 : 0;

        for (int node = blockIdx.x * 16 + wave * 4 + grp; node < n; node += NB * 16) {
            uint4 v = *(const uint4*)(gbuf + (size_t)node * HH + cb);
            unsigned u[4] = {v.x, v.y, v.z, v.w};
            float x = 0.f;
#pragma unroll
            for (int j = 0; j < 4; ++j) {
                float f0 = __builtin_bit_cast(float, u[j] << 16);
                float f1 = __builtin_bit_cast(float, u[j] & 0xffff0000u);
                x += fmaxf(f0 * sc8[2 * j] + sh8[2 * j], 0.f) * w8[2 * j];
                x += fmaxf(f1 * sc8[2 * j + 1] + sh8[2 * j + 1], 0.f) * w8[2 * j + 1];
            }
#pragma unroll
            for (int off = 8; off; off >>= 1) x += __shfl_xor(x, off);
            if (p == 0) {
                float r = x + bb;
                if (flag) ((ushort_t*)outv)[node] = f2bf(r);
                else      ((float*)outv)[node] = r;
            }
        }
    }
}

// ================= launch =================
extern "C" void kernel_launch(void* const* d_in, const int* in_sizes, int n_in,
                              void* d_out, int out_size, void* d_ws, size_t ws_size,
                              hipStream_t stream) {
    const int DIN = 256;
    const int N = in_sizes[0] / DIN;
    const int E = in_sizes[1];

    const void* x   = d_in[0];
    const int*  src = (const int*)d_in[1];
    const int*  dst = (const int*)d_in[2];
    const void* W1  = d_in[3];
    const void* b1  = d_in[4];
    const void* g1  = d_in[5];
    const void* be1 = d_in[6];
    const void* W2  = d_in[7];
    const void* b2  = d_in[8];
    const void* g2  = d_in[9];
    const void* be2 = d_in[10];
    const void* W3  = d_in[11];
    const void* b3  = d_in[12];
    const void* g3  = d_in[13];
    const void* be3 = d_in[14];
    const void* Wf  = d_in[15];
    const void* bfp = d_in[16];
    const ushort_t* flagRef = (const ushort_t*)g1;

    char* base = (char*)d_ws;
    size_t off = 0;
    auto carve = [&](size_t bytes) -> void* {
        void* p = base + off;
        off += (bytes + 255) & ~(size_t)255;
        return p;
    };
    int*      counts = (int*)carve((size_t)N * 4);
    float*    stats  = (float*)carve((size_t)3 * 2 * STAT_SLICES * HH * 4);
    int*      bar    = (int*)carve((size_t)(BAR_LINES * 64 + 128) * 4); // lines | mid | rel
    size_t    zbytes = off;                       // memset range [0, zbytes)
    float*    dis    = (float*)carve((size_t)N * 4);
    int*      rowptr = (int*)carve((size_t)(N + 1) * 4);
    int*      partial= (int*)carve(256 * 4);
    uint2*    erec   = (uint2*)carve((size_t)E * 8);
    ushort_t* Wt1    = (ushort_t*)carve((size_t)128 * 256 * 2);
    ushort_t* Wt2    = (ushort_t*)carve((size_t)128 * 128 * 2);
    ushort_t* Wt3    = (ushort_t*)carve((size_t)128 * 128 * 2);
    ushort_t* tbuf   = (ushort_t*)carve((size_t)N * HH * 2);
    ushort_t* gbuf   = (ushort_t*)carve((size_t)N * HH * 2);
    float*    cvec   = (float*)carve((size_t)1281 * 4);

    const int nbScan = (N + 2047) / 2048;
    const int histB  = (E + 255) / 256;
    const int disB   = (N + 255) / 256;
    const int mm1B   = 1024;

    hipMemsetAsync(d_ws, 0, zbytes, stream);   // counts + stats + barrier

    preK<<<histB + 256 + 1, 256, 0, stream>>>(dst, counts, E, W1, Wt1, W2, Wt2, W3, Wt3,
                                              g1, b1, b2, b3, g2, g3, be1, be2, be3, Wf, bfp,
                                              cvec, histB);
    scanAdisK<<<nbScan + disB, 256, 0, stream>>>(counts, partial, dis, N, nbScan);
    mm1scanCK<<<nbScan + mm1B, 256, 0, stream>>>(x, Wt1, tbuf, N, flagRef,
                                                 counts, partial, rowptr, nbScan);
    fusedK<<<FB, 256, 0, stream>>>(src, dst, rowptr, counts, dis, erec, E,
                                   Wt2, Wt3, tbuf, gbuf, cvec, stats,
                                   d_out, N, flagRef,
                                   bar, bar + BAR_LINES * 64, bar + BAR_LINES * 64 + 64);
}